// Round 1
// baseline (1720.019 us; speedup 1.0000x reference)
//
#include <hip/hip_runtime.h>
#include <hip/hip_bf16.h>

#define T_STEPS 64
#define B_DIM 2048
#define U_DIM 1024
#define KITERS 32   // K-steps of 32 over U=1024

typedef __attribute__((ext_vector_type(8))) _Float16 h8;
typedef __attribute__((ext_vector_type(4))) float f4;

__device__ __forceinline__ void async_cp16(const _Float16* g, _Float16* l) {
    __builtin_amdgcn_global_load_lds((const __attribute__((address_space(1))) void*)g,
                                     (__attribute__((address_space(3))) void*)l,
                                     16, 0, 0);
}

// ---------------- init kernels ----------------

// R: [U][2U] f32 row-major -> Rt: [2U][U] f16 (B^T layout)
__global__ void transpose_R(const float* __restrict__ R, _Float16* __restrict__ Rt) {
    __shared__ float tile[32][33];
    int nb = blockIdx.x * 32;
    int kb = blockIdx.y * 32;
    int tx = threadIdx.x, ty = threadIdx.y;   // block (32,8)
    #pragma unroll
    for (int i = ty; i < 32; i += 8)
        tile[i][tx] = R[(size_t)(kb + i) * (2 * U_DIM) + nb + tx];
    __syncthreads();
    #pragma unroll
    for (int i = ty; i < 32; i += 8)
        Rt[(size_t)(nb + i) * U_DIM + kb + tx] = (_Float16)tile[tx][i];
}

__global__ void init_state(const float* __restrict__ c0, _Float16* __restrict__ h0,
                           float* __restrict__ y, unsigned* __restrict__ bar) {
    int i = blockIdx.x * 256 + threadIdx.x;
    h0[i] = (_Float16)c0[i];
    if (i < 3 * B_DIM) y[i] = 0.f;
    if (i < 256) bar[i] = 0u;
}

// ---------------- persistent fused kernel ----------------
// Grid 256 = 32 u-chunks x 8 b-chunks, 1 block/CU (160 KB LDS).
// b-chunk = blockIdx%8 -> all 32 blocks of a chunk land on one XCD under the
// observed round-robin dispatch, so the h ping-pong never leaves that XCD's L2.
// B-panel (Rf|Rc for this block's 32 cols, full K) is LDS-resident for all 63
// GEMM steps. Steps are separated by a per-chunk 32-block cumulative barrier.
// Mapping is *verified at runtime* via HW_REG_XCC_ID; if a chunk spans XCDs we
// fall back to full agent release fences (correctness never depends on mapping).
__global__ __launch_bounds__(256, 1) void persist(
    _Float16* __restrict__ h0, _Float16* __restrict__ h1,
    const _Float16* __restrict__ Rt,
    const float* __restrict__ x1_0, const float* __restrict__ x2_0,
    const float* __restrict__ kern, const float* __restrict__ bias,
    const float* __restrict__ okern,
    float* y,                         // [3][B]  (agent-scope atomics only)
    const float* __restrict__ inputs, // [T][B]
    float* __restrict__ out,          // [T][B]
    unsigned* bar)                    // 8 groups x 32-uint padded lines
{
    // 128 KB persistent B: [gate][nt][kt][16 rows x 32 swizzled halfs]
    __shared__ __align__(16) _Float16 lB[2][2][KITERS][512];
    // 32 KB A ring: [wave][stage 2][j=16-row region][512]  (overlaid by lC/x1s in epilogue)
    __shared__ __align__(16) _Float16 lA[4][2][4][512];

    const int tid    = threadIdx.x;
    const int wid    = tid >> 6;
    const int lane   = tid & 63;
    const int lane15 = lane & 15;
    const int quad   = lane >> 4;
    const int bid    = blockIdx.x;
    const int b0     = (bid & 7) * 256;       // b-chunk <-> XCD (perf heuristic only)
    const int u0     = (bid >> 3) * 32;
    const bool ub0   = (bid >> 3) == 0;
    const int wrow   = wid * 64;              // wave's 64 A-rows
    const int srow   = lane >> 2;
    const int schnk  = ((lane & 3) ^ (srow & 3)) * 8;   // XOR-swizzled K-chunk
    const int sw     = (quad ^ (lane15 & 3)) * 8;
    const int myb    = b0 + tid;              // this thread's owned batch row
    unsigned* ctr   = &bar[(bid & 7) * 32];
    unsigned* xmask = &bar[(bid & 7) * 32 + 8];

    // ---- issue persistent-B DMAs (128 x 1KB regions, 32 per wave) ----
    #pragma unroll
    for (int gate = 0; gate < 2; ++gate)
        #pragma unroll
        for (int nt = 0; nt < 2; ++nt)
            #pragma unroll
            for (int i = 0; i < 8; ++i) {
                const int kt = wid + i * 4;
                async_cp16(Rt + (size_t)(gate * U_DIM + u0 + nt * 16 + srow) * U_DIM + kt * 32 + schnk,
                           &lB[gate][nt][kt][0]);
            }

    // ---- XCD purity probe + first rendezvous (overlaps B DMA flight) ----
    int* flag = (int*)&lA[0][0][0][0];
    if (tid == 0) {
        const unsigned xcc = (unsigned)__builtin_amdgcn_s_getreg(63508) & 31u; // HW_REG_XCC_ID, size 32
        __hip_atomic_fetch_or(xmask, 1u << xcc, __ATOMIC_RELAXED, __HIP_MEMORY_SCOPE_AGENT);
        __hip_atomic_fetch_add(ctr, 1u, __ATOMIC_RELAXED, __HIP_MEMORY_SCOPE_AGENT);
        while (__hip_atomic_load(ctr, __ATOMIC_RELAXED, __HIP_MEMORY_SCOPE_AGENT) < 32u)
            __builtin_amdgcn_s_sleep(2);
        const unsigned m = __hip_atomic_load(xmask, __ATOMIC_RELAXED, __HIP_MEMORY_SCOPE_AGENT);
        *flag = (__popc(m) == 1) ? 1 : 0;
    }
    __syncthreads();
    const bool xcd_pure = (*flag != 0);

    // ---- loop-invariant epilogue constants ----
    float kf[2], kc[2], bf_[2], bc_[2], ok_[2];
    #pragma unroll
    for (int nt = 0; nt < 2; ++nt) {
        const int u = u0 + nt * 16 + lane15;
        kf[nt]  = kern[u];        kc[nt]  = kern[U_DIM + u];
        bf_[nt] = bias[u];        bc_[nt] = bias[U_DIM + u];
        ok_[nt] = okern[u];
    }

    // integrator state lives in registers for all 64 steps
    float x1r = x1_0[myb];
    float x2r = x2_0[myb];

    __builtin_amdgcn_s_waitcnt(0x0F70);   // vmcnt(0): B panel resident
    __syncthreads();                      // all waves' B visible; flag consumed

    _Float16* hA_ = h0;
    _Float16* hB_ = h1;
    _Float16* lC  = &lA[0][0][0][0];          // 256 x 40 halfs = 20 KB overlay
    float*    x1s = (float*)&lA[2][1][0][0];  // 256 f32 at half-offset 10240

    #pragma unroll 1
    for (int t = 0; t < T_STEPS; ++t) {
        // ---- integrator update (y finalized by previous step's barrier) ----
        if (t > 0) {
            const float ip = inputs[(size_t)(t - 1) * B_DIM + myb];
            const float yp = __hip_atomic_load(&y[((t + 2) % 3) * B_DIM + myb],
                                               __ATOMIC_RELAXED, __HIP_MEMORY_SCOPE_AGENT);
            x1r = x1r + x2r;
            x2r = x2r + ip * yp;
        }
        if (ub0) {
            if (t > 0) out[(size_t)(t - 1) * B_DIM + myb] = x1r;
            if (t == T_STEPS - 1)
                out[(size_t)(T_STEPS - 1) * B_DIM + myb] = x1r + x2r;  // x1_{T}
            else
                __hip_atomic_store(&y[((t + 1) % 3) * B_DIM + myb], 0.f,
                                   __ATOMIC_RELAXED, __HIP_MEMORY_SCOPE_AGENT);
        }
        if (t == T_STEPS - 1) break;   // step-63 GEMM output is never consumed

        // ---- h gate values to registers (local-XCD L2 reads) ----
        _Float16 hv[4][2][4];
        #pragma unroll
        for (int mt = 0; mt < 4; ++mt)
            #pragma unroll
            for (int nt = 0; nt < 2; ++nt)
                #pragma unroll
                for (int reg = 0; reg < 4; ++reg)
                    hv[mt][nt][reg] = hA_[(size_t)(b0 + wrow + mt * 16 + quad * 4 + reg) * U_DIM
                                          + u0 + nt * 16 + lane15];

        auto stageA = [&](int st, int kt) {
            const int k0 = kt * 32;
            #pragma unroll
            for (int j = 0; j < 4; ++j)
                async_cp16(hA_ + (size_t)(b0 + wrow + j * 16 + srow) * U_DIM + k0 + schnk,
                           &lA[wid][st][j][0]);
        };

        f4 accF[4][2], accC[4][2];
        #pragma unroll
        for (int mt = 0; mt < 4; ++mt)
            #pragma unroll
            for (int nt = 0; nt < 2; ++nt) {
                accF[mt][nt] = (f4){0.f, 0.f, 0.f, 0.f};
                accC[mt][nt] = (f4){0.f, 0.f, 0.f, 0.f};
            }

        auto body = [&](int kt) {
            const int st = kt & 1;
            h8 af[4], bff[2], bfc[2];
            #pragma unroll
            for (int mt = 0; mt < 4; ++mt)
                af[mt] = *(const h8*)&lA[wid][st][mt][lane15 * 32 + sw];
            #pragma unroll
            for (int nt = 0; nt < 2; ++nt) {
                bff[nt] = *(const h8*)&lB[0][nt][kt][lane15 * 32 + sw];
                bfc[nt] = *(const h8*)&lB[1][nt][kt][lane15 * 32 + sw];
            }
            #pragma unroll
            for (int mt = 0; mt < 4; ++mt)
                #pragma unroll
                for (int nt = 0; nt < 2; ++nt) {
                    accF[mt][nt] = __builtin_amdgcn_mfma_f32_16x16x32_f16(af[mt], bff[nt], accF[mt][nt], 0, 0, 0);
                    accC[mt][nt] = __builtin_amdgcn_mfma_f32_16x16x32_f16(af[mt], bfc[nt], accC[mt][nt], 0, 0, 0);
                }
        };

        // ---- barrier-free K-loop: per-wave 2-deep ring, self-paced vmcnt ----
        stageA(0, 0);
        stageA(1, 1);
        for (int kt = 0; kt < KITERS - 2; ++kt) {
            __builtin_amdgcn_s_waitcnt(0x0F74);   // vmcnt(4): stage kt landed
            body(kt);
            stageA(kt & 1, kt + 2);
        }
        __builtin_amdgcn_s_waitcnt(0x0F74);
        body(KITERS - 2);
        __builtin_amdgcn_s_waitcnt(0x0F70);       // vmcnt(0)
        body(KITERS - 1);

        __syncthreads();      // all waves done with lA ring -> overlay safe
        x1s[tid] = x1r;
        __syncthreads();

        // ---- epilogue: gates, c -> lC overlay, y partials ----
        float* ycur = y + (t % 3) * B_DIM;
        #pragma unroll
        for (int mt = 0; mt < 4; ++mt) {
            const int rlb = wrow + mt * 16 + quad * 4;
            float psum[4] = {0.f, 0.f, 0.f, 0.f};
            #pragma unroll
            for (int nt = 0; nt < 2; ++nt) {
                const int ul = nt * 16 + lane15;
                #pragma unroll
                for (int reg = 0; reg < 4; ++reg) {
                    const int rl = rlb + reg;
                    const float x1 = x1s[rl];
                    const float xf = accF[mt][nt][reg] + x1 * kf[nt] + bf_[nt];
                    const float xc = accC[mt][nt][reg] + x1 * kc[nt] + bc_[nt];
                    const float fg = 1.f / (1.f + __expf(-xf));
                    const float th = 1.f - 2.f / (1.f + __expf(2.f * xc));
                    const float cv = fg * (float)hv[mt][nt][reg] + (1.f - fg) * th;
                    lC[rl * 40 + ul] = (_Float16)cv;      // stride 40 breaks bank aliasing
                    psum[reg] += cv * ok_[nt];
                }
            }
            #pragma unroll
            for (int reg = 0; reg < 4; ++reg) {
                float s = psum[reg];
                s += __shfl_xor(s, 1);
                s += __shfl_xor(s, 2);
                s += __shfl_xor(s, 4);
                s += __shfl_xor(s, 8);
                if (lane15 == 0) atomicAdd(&ycur[b0 + rlb + reg], s);
            }
        }

        // ---- coalesced c write-out ----
        __syncthreads();
        #pragma unroll
        for (int j = 0; j < 4; ++j) {
            const int idx = j * 256 + tid;       // 1024 uint4 = 256 rows x 4
            const int row = idx >> 2;
            const int col = idx & 3;
            *(uint4*)&hB_[(size_t)(b0 + row) * U_DIM + u0 + col * 8] =
                *(const uint4*)&lC[row * 40 + col * 8];
        }

        { _Float16* tmp = hA_; hA_ = hB_; hB_ = tmp; }

        // ---- per-chunk 32-block barrier (cumulative counter) ----
        // pure path: __syncthreads' vmcnt drain puts h in the shared XCD L2;
        // impure fallback: full agent release (L2 writeback) before arrival.
        if (!xcd_pure) __builtin_amdgcn_fence(__ATOMIC_RELEASE, "agent");
        __syncthreads();
        if (tid == 0) {
            __hip_atomic_fetch_add(ctr, 1u, __ATOMIC_RELAXED, __HIP_MEMORY_SCOPE_AGENT);
            while (__hip_atomic_load(ctr, __ATOMIC_RELAXED, __HIP_MEMORY_SCOPE_AGENT)
                   < 32u * (unsigned)(t + 2))            // +32 from the startup rendezvous
                __builtin_amdgcn_s_sleep(2);
        }
        __syncthreads();
        __builtin_amdgcn_fence(__ATOMIC_ACQUIRE, "agent");   // invalidate L1 before next-step h reads
    }
}

// ---------------- host ----------------
extern "C" void kernel_launch(void* const* d_in, const int* in_sizes, int n_in,
                              void* d_out, int out_size, void* d_ws, size_t ws_size,
                              hipStream_t stream) {
    const float* inputs = (const float*)d_in[0];
    const float* x1_0   = (const float*)d_in[1];
    const float* x2_0   = (const float*)d_in[2];
    const float* c0     = (const float*)d_in[3];
    const float* kern   = (const float*)d_in[4];
    const float* rker   = (const float*)d_in[5];
    const float* bias   = (const float*)d_in[6];
    const float* okern  = (const float*)d_in[7];
    float* out = (float*)d_out;

    _Float16* Rt = (_Float16*)d_ws;                       // 4 MB
    _Float16* h0 = Rt + (size_t)2 * U_DIM * U_DIM;        // 4 MB
    _Float16* h1 = h0 + (size_t)B_DIM * U_DIM;            // 4 MB
    float* y = (float*)(h1 + (size_t)B_DIM * U_DIM);      // 3*B
    unsigned* bar = (unsigned*)(y + 3 * B_DIM);           // 256 uints

    transpose_R<<<dim3(64, 32), dim3(32, 8), 0, stream>>>(rker, Rt);
    init_state<<<dim3(B_DIM * U_DIM / 256), dim3(256), 0, stream>>>(c0, h0, y, bar);
    persist<<<dim3(256), dim3(256), 0, stream>>>(h0, h1, Rt, x1_0, x2_0,
                                                 kern, bias, okern, y, inputs, out, bar);
}

// Round 2
// 1266.781 us; speedup vs baseline: 1.3578x; 1.3578x over previous
//
#include <hip/hip_runtime.h>
#include <hip/hip_bf16.h>

#define T_STEPS 64
#define B_DIM 2048
#define U_DIM 1024
#define KITERS 32   // K-steps of 32 over U=1024

typedef __attribute__((ext_vector_type(8))) _Float16 h8;
typedef __attribute__((ext_vector_type(4))) float f4;

#define WAIT_VM4   __builtin_amdgcn_s_waitcnt(0x0F74)   // vmcnt(4), lgkm/exp no-wait
#define WAIT_VM0   __builtin_amdgcn_s_waitcnt(0x0F70)   // vmcnt(0)
#define WAIT_LGKM0 __builtin_amdgcn_s_waitcnt(0xC07F)   // lgkmcnt(0), vm/exp no-wait

__device__ __forceinline__ void async_cp16(const _Float16* g, _Float16* l) {
    __builtin_amdgcn_global_load_lds((const __attribute__((address_space(1))) void*)g,
                                     (__attribute__((address_space(3))) void*)l,
                                     16, 0, 0);
}
// SC0 (L1-bypass) variant: reads served by the XCD-coherent L2 -> no acquire
// fence needed in the XCD-pure path.
__device__ __forceinline__ void async_cp16_sc0(const _Float16* g, _Float16* l) {
    __builtin_amdgcn_global_load_lds((const __attribute__((address_space(1))) void*)g,
                                     (__attribute__((address_space(3))) void*)l,
                                     16, 0, 1);
}

// ---------------- init kernels ----------------

// R: [U][2U] f32 row-major -> Rt: [2U][U] f16 (B^T layout)
__global__ void transpose_R(const float* __restrict__ R, _Float16* __restrict__ Rt) {
    __shared__ float tile[32][33];
    int nb = blockIdx.x * 32;
    int kb = blockIdx.y * 32;
    int tx = threadIdx.x, ty = threadIdx.y;   // block (32,8)
    #pragma unroll
    for (int i = ty; i < 32; i += 8)
        tile[i][tx] = R[(size_t)(kb + i) * (2 * U_DIM) + nb + tx];
    __syncthreads();
    #pragma unroll
    for (int i = ty; i < 32; i += 8)
        Rt[(size_t)(nb + i) * U_DIM + kb + tx] = (_Float16)tile[tx][i];
}

__global__ void init_state(const float* __restrict__ c0, _Float16* __restrict__ h0,
                           float* __restrict__ y, unsigned* __restrict__ bar) {
    int i = blockIdx.x * 256 + threadIdx.x;
    h0[i] = (_Float16)c0[i];
    if (i < 3 * B_DIM) y[i] = 0.f;
    if (i < 256) bar[i] = 0u;
}

// ---------------- persistent fused kernel ----------------
// Grid 256 = 32 u-chunks x 8 b-chunks, 1 block/CU (160 KB LDS).
// b-chunk = blockIdx%8 -> one XCD under round-robin dispatch; h ping-pong stays
// in that XCD's L2. Pure path uses SC0 loads (L1-bypass) + write-through stores
// -> NO per-step agent fences (agent acquire would invalidate L2!).
// Impure fallback (probed via HW_REG_XCC_ID) keeps full fences.
__global__ __launch_bounds__(256, 1) void persist(
    _Float16* __restrict__ h0, _Float16* __restrict__ h1,
    const _Float16* __restrict__ Rt,
    const float* __restrict__ x1_0, const float* __restrict__ x2_0,
    const float* __restrict__ kern, const float* __restrict__ bias,
    const float* __restrict__ okern,
    float* y,                         // [3][B]  (agent-scope atomics only)
    const float* __restrict__ inputs, // [T][B]
    float* __restrict__ out,          // [T][B]
    unsigned* bar)                    // 8 groups x 32-uint padded lines
{
    // 128 KB persistent B: [gate][nt][kt][16 rows x 32 swizzled halfs]
    __shared__ __align__(16) _Float16 lB[2][2][KITERS][512];
    // 32 KB A ring: [wave][stage 2][j=16-row region][512]  (epilogue overlay)
    __shared__ __align__(16) _Float16 lA[4][2][4][512];

    const int tid    = threadIdx.x;
    const int wid    = tid >> 6;
    const int lane   = tid & 63;
    const int lane15 = lane & 15;
    const int quad   = lane >> 4;
    const int bid    = blockIdx.x;
    const int b0     = (bid & 7) * 256;
    const int u0     = (bid >> 3) * 32;
    const bool ub0   = (bid >> 3) == 0;
    const int wrow   = wid * 64;
    const int srow   = lane >> 2;
    // 3-term XOR swizzle: consecutive-8-lane read windows hit all 8 bank-groups
    const int schnk  = (((lane & 3) ^ (srow & 3) ^ ((srow >> 2) & 3)) * 8);
    const int sw     = ((quad ^ (lane15 & 3) ^ ((lane15 >> 2) & 3)) * 8);
    const int rdoff  = lane15 * 32 + sw;
    const int myb    = b0 + tid;
    unsigned* ctr   = &bar[(bid & 7) * 32];
    unsigned* xmask = &bar[(bid & 7) * 32 + 8];

    // ---- issue persistent-B DMAs (128 x 1KB regions, 32 per wave) ----
    #pragma unroll
    for (int gate = 0; gate < 2; ++gate)
        #pragma unroll
        for (int nt = 0; nt < 2; ++nt)
            #pragma unroll
            for (int i = 0; i < 8; ++i) {
                const int kt = wid + i * 4;
                async_cp16(Rt + (size_t)(gate * U_DIM + u0 + nt * 16 + srow) * U_DIM + kt * 32 + schnk,
                           &lB[gate][nt][kt][0]);
            }

    // ---- XCD purity probe + first rendezvous (overlaps B DMA flight) ----
    int* flag = (int*)&lA[0][0][0][0];
    if (tid == 0) {
        const unsigned xcc = (unsigned)__builtin_amdgcn_s_getreg(63508) & 31u; // HW_REG_XCC_ID
        __hip_atomic_fetch_or(xmask, 1u << xcc, __ATOMIC_RELAXED, __HIP_MEMORY_SCOPE_AGENT);
        __hip_atomic_fetch_add(ctr, 1u, __ATOMIC_RELAXED, __HIP_MEMORY_SCOPE_AGENT);
        while (__hip_atomic_load(ctr, __ATOMIC_RELAXED, __HIP_MEMORY_SCOPE_AGENT) < 32u)
            __builtin_amdgcn_s_sleep(1);
        const unsigned m = __hip_atomic_load(xmask, __ATOMIC_RELAXED, __HIP_MEMORY_SCOPE_AGENT);
        *flag = (__popc(m) == 1) ? 1 : 0;
    }
    __syncthreads();
    const bool xcd_pure = (*flag != 0);

    // ---- loop-invariant epilogue constants ----
    float kf[2], kc[2], bf_[2], bc_[2], ok_[2];
    #pragma unroll
    for (int nt = 0; nt < 2; ++nt) {
        const int u = u0 + nt * 16 + lane15;
        kf[nt]  = kern[u];        kc[nt]  = kern[U_DIM + u];
        bf_[nt] = bias[u];        bc_[nt] = bias[U_DIM + u];
        ok_[nt] = okern[u];
    }

    // ---- h gate values: register-carried across ALL steps ----
    // At step t, hv must hold c_{t-1}[row, u0+col] -- exactly what THIS thread
    // computed in step t-1's epilogue (identical (row,col) mapping). Load from
    // c0 once; thereafter update in-register. Zero global h gate-reads/step.
    _Float16 hv[4][2][4];
    #pragma unroll
    for (int mt = 0; mt < 4; ++mt)
        #pragma unroll
        for (int nt = 0; nt < 2; ++nt)
            #pragma unroll
            for (int reg = 0; reg < 4; ++reg)
                hv[mt][nt][reg] = h0[(size_t)(b0 + wrow + mt * 16 + quad * 4 + reg) * U_DIM
                                     + u0 + nt * 16 + lane15];

    // integrator state lives in registers for all 64 steps
    float x1r = x1_0[myb];
    float x2r = x2_0[myb];

    WAIT_VM0;            // B panel + hv resident
    __syncthreads();     // all waves' B visible; flag consumed

    _Float16* hA_ = h0;
    _Float16* hB_ = h1;
    _Float16* lC  = &lA[0][0][0][0];          // 256 x 40 halfs = 20 KB overlay
    float*    x1s = (float*)&lA[2][1][0][0];  // 256 f32 at half-offset 10240

    #pragma unroll 1
    for (int t = 0; t < T_STEPS; ++t) {
        // ---- integrator update (y finalized by previous step's barrier) ----
        if (t > 0) {
            const float ip = inputs[(size_t)(t - 1) * B_DIM + myb];
            const float yp = __hip_atomic_load(&y[((t + 2) % 3) * B_DIM + myb],
                                               __ATOMIC_RELAXED, __HIP_MEMORY_SCOPE_AGENT);
            x1r = x1r + x2r;
            x2r = x2r + ip * yp;
        }
        if (ub0) {
            if (t > 0) out[(size_t)(t - 1) * B_DIM + myb] = x1r;
            if (t == T_STEPS - 1)
                out[(size_t)(T_STEPS - 1) * B_DIM + myb] = x1r + x2r;  // x1_{T}
            else
                __hip_atomic_store(&y[((t + 1) % 3) * B_DIM + myb], 0.f,
                                   __ATOMIC_RELAXED, __HIP_MEMORY_SCOPE_AGENT);
        }
        if (t == T_STEPS - 1) break;   // step-63 GEMM output is never consumed

        auto stageA = [&](int st, int kt) {
            const int k0 = kt * 32;
            #pragma unroll
            for (int j = 0; j < 4; ++j)
                async_cp16_sc0(hA_ + (size_t)(b0 + wrow + j * 16 + srow) * U_DIM + k0 + schnk,
                               &lA[wid][st][j][0]);
        };

        f4 accF[4][2], accC[4][2];
        #pragma unroll
        for (int mt = 0; mt < 4; ++mt)
            #pragma unroll
            for (int nt = 0; nt < 2; ++nt) {
                accF[mt][nt] = (f4){0.f, 0.f, 0.f, 0.f};
                accC[mt][nt] = (f4){0.f, 0.f, 0.f, 0.f};
            }

        // register-double-buffered fragment pipeline
        h8 afA[4], bfA[2], bcA[2], afB[4], bfB[2], bcB[2];
        auto readfr = [&](int kt, h8* af, h8* bf, h8* bc) {
            const int st = kt & 1;
            #pragma unroll
            for (int mt = 0; mt < 4; ++mt)
                af[mt] = *(const h8*)&lA[wid][st][mt][rdoff];
            #pragma unroll
            for (int nt = 0; nt < 2; ++nt) {
                bf[nt] = *(const h8*)&lB[0][nt][kt][rdoff];
                bc[nt] = *(const h8*)&lB[1][nt][kt][rdoff];
            }
        };
        auto domfma = [&](h8* af, h8* bf, h8* bc) {
            #pragma unroll
            for (int mt = 0; mt < 4; ++mt)
                #pragma unroll
                for (int nt = 0; nt < 2; ++nt) {
                    accF[mt][nt] = __builtin_amdgcn_mfma_f32_16x16x32_f16(af[mt], bf[nt], accF[mt][nt], 0, 0, 0);
                    accC[mt][nt] = __builtin_amdgcn_mfma_f32_16x16x32_f16(af[mt], bc[nt], accC[mt][nt], 0, 0, 0);
                }
        };

        // ---- K-loop: ds-read kt+1 BEFORE MFMA kt (latency hidden in-wave) ----
        stageA(0, 0);
        stageA(1, 1);
        WAIT_VM4;                    // stage 0 landed
        readfr(0, afA, bfA, bcA);
        for (int kt2 = 0; kt2 < KITERS - 2; kt2 += 2) {
            WAIT_LGKM0;              // frag reads done before ring overwrite
            stageA(kt2 & 1, kt2 + 2);
            WAIT_VM4;                // stage kt2+1 landed
            readfr(kt2 + 1, afB, bfB, bcB);
            domfma(afA, bfA, bcA);   // frags kt2
            WAIT_LGKM0;
            stageA((kt2 + 1) & 1, kt2 + 3);
            WAIT_VM4;                // stage kt2+2 landed
            readfr(kt2 + 2, afA, bfA, bcA);
            domfma(afB, bfB, bcB);   // frags kt2+1
        }
        WAIT_VM0;                    // stage 31 landed
        readfr(KITERS - 1, afB, bfB, bcB);
        domfma(afA, bfA, bcA);       // frags 30
        domfma(afB, bfB, bcB);       // frags 31

        __syncthreads();   // all waves done with lA ring -> overlay safe
        x1s[tid] = x1r;
        __syncthreads();

        // ---- epilogue: gates, c -> lC overlay + hv register carry, y partials ----
        float* ycur = y + (t % 3) * B_DIM;
        #pragma unroll
        for (int mt = 0; mt < 4; ++mt) {
            const int rlb = wrow + mt * 16 + quad * 4;
            float psum[4] = {0.f, 0.f, 0.f, 0.f};
            #pragma unroll
            for (int nt = 0; nt < 2; ++nt) {
                const int ul = nt * 16 + lane15;
                #pragma unroll
                for (int reg = 0; reg < 4; ++reg) {
                    const int rl = rlb + reg;
                    const float x1 = x1s[rl];
                    const float xf = accF[mt][nt][reg] + x1 * kf[nt] + bf_[nt];
                    const float xc = accC[mt][nt][reg] + x1 * kc[nt] + bc_[nt];
                    const float fg = 1.f / (1.f + __expf(-xf));
                    const float th = 1.f - 2.f / (1.f + __expf(2.f * xc));
                    const float cv = fg * (float)hv[mt][nt][reg] + (1.f - fg) * th;
                    hv[mt][nt][reg] = (_Float16)cv;       // gate value for step t+1
                    lC[rl * 40 + ul] = (_Float16)cv;
                    psum[reg] += cv * ok_[nt];
                }
            }
            #pragma unroll
            for (int reg = 0; reg < 4; ++reg) {
                float s = psum[reg];
                s += __shfl_xor(s, 1);
                s += __shfl_xor(s, 2);
                s += __shfl_xor(s, 4);
                s += __shfl_xor(s, 8);
                if (lane15 == 0) atomicAdd(&ycur[b0 + rlb + reg], s);
            }
        }

        // ---- coalesced c write-out (plain stores: vector L1 is write-through) ----
        __syncthreads();
        #pragma unroll
        for (int j = 0; j < 4; ++j) {
            const int idx = j * 256 + tid;       // 1024 uint4 = 256 rows x 4
            const int row = idx >> 2;
            const int col = idx & 3;
            *(uint4*)&hB_[(size_t)(b0 + row) * U_DIM + u0 + col * 8] =
                *(const uint4*)&lC[row * 40 + col * 8];
        }

        { _Float16* tmp = hA_; hA_ = hB_; hB_ = tmp; }

        // ---- per-chunk 32-block barrier (cumulative counter) ----
        // pure path: __syncthreads' vmcnt drain publishes h to the shared XCD
        // L2; consumers read via SC0 -> no fences. impure: full agent fences.
        if (!xcd_pure) __builtin_amdgcn_fence(__ATOMIC_RELEASE, "agent");
        __syncthreads();
        if (tid == 0) {
            __hip_atomic_fetch_add(ctr, 1u, __ATOMIC_RELAXED, __HIP_MEMORY_SCOPE_AGENT);
            while (__hip_atomic_load(ctr, __ATOMIC_RELAXED, __HIP_MEMORY_SCOPE_AGENT)
                   < 32u * (unsigned)(t + 2))            // +32 startup rendezvous
                __builtin_amdgcn_s_sleep(1);
        }
        __syncthreads();
        if (!xcd_pure) __builtin_amdgcn_fence(__ATOMIC_ACQUIRE, "agent");
    }
}

// ---------------- host ----------------
extern "C" void kernel_launch(void* const* d_in, const int* in_sizes, int n_in,
                              void* d_out, int out_size, void* d_ws, size_t ws_size,
                              hipStream_t stream) {
    const float* inputs = (const float*)d_in[0];
    const float* x1_0   = (const float*)d_in[1];
    const float* x2_0   = (const float*)d_in[2];
    const float* c0     = (const float*)d_in[3];
    const float* kern   = (const float*)d_in[4];
    const float* rker   = (const float*)d_in[5];
    const float* bias   = (const float*)d_in[6];
    const float* okern  = (const float*)d_in[7];
    float* out = (float*)d_out;

    _Float16* Rt = (_Float16*)d_ws;                       // 4 MB
    _Float16* h0 = Rt + (size_t)2 * U_DIM * U_DIM;        // 4 MB
    _Float16* h1 = h0 + (size_t)B_DIM * U_DIM;            // 4 MB
    float* y = (float*)(h1 + (size_t)B_DIM * U_DIM);      // 3*B
    unsigned* bar = (unsigned*)(y + 3 * B_DIM);           // 256 uints

    transpose_R<<<dim3(64, 32), dim3(32, 8), 0, stream>>>(rker, Rt);
    init_state<<<dim3(B_DIM * U_DIM / 256), dim3(256), 0, stream>>>(c0, h0, y, bar);
    persist<<<dim3(256), dim3(256), 0, stream>>>(h0, h1, Rt, x1_0, x2_0,
                                                 kern, bias, okern, y, inputs, out, bar);
}